// Round 1
// baseline (960.138 us; speedup 1.0000x reference)
//
#include <hip/hip_runtime.h>
#include <hip/hip_bf16.h>
#include <cstddef>

#define NNODES 50000
#define NEDGES 800000
#define HID 128
#define NHEAD 8
#define HDIM 16

static inline size_t align_up(size_t x, size_t a) { return (x + a - 1) & ~(a - 1); }

// ---------------------------------------------------------------- CSR build
__global__ void hist_kernel(const int* __restrict__ edge, int* __restrict__ cnt) {
    int e = blockIdx.x * blockDim.x + threadIdx.x;
    if (e < NEDGES) {
        int d = edge[NEDGES + e];
        atomicAdd(&cnt[d], 1);
    }
}

__global__ __launch_bounds__(1024) void scan_kernel(const int* __restrict__ cnt,
                                                    int* __restrict__ offs) {
    __shared__ int sm[1024];
    __shared__ int carry;
    int t = threadIdx.x;
    if (t == 0) { carry = 0; offs[0] = 0; }
    __syncthreads();
    for (int base = 0; base < NNODES; base += 1024) {
        int i = base + t;
        int v = (i < NNODES) ? cnt[i] : 0;
        sm[t] = v;
        __syncthreads();
        for (int off = 1; off < 1024; off <<= 1) {
            int x = (t >= off) ? sm[t - off] : 0;
            __syncthreads();
            sm[t] += x;
            __syncthreads();
        }
        if (i < NNODES) offs[i + 1] = carry + sm[t];
        __syncthreads();
        if (t == 0) carry += sm[1023];
        __syncthreads();
    }
}

__global__ void scatter_kernel(const int* __restrict__ edge, const int* __restrict__ offs,
                               int* __restrict__ cursor, int* __restrict__ csr) {
    int e = blockIdx.x * blockDim.x + threadIdx.x;
    if (e < NEDGES) {
        int s = edge[e];
        int d = edge[NEDGES + e];
        int p = offs[d] + atomicAdd(&cursor[d], 1);
        csr[p] = s;
    }
}

// ---------------------------------------------------------------- GEMM  [N,128] x [128,128]
#define GROWS 64
__global__ __launch_bounds__(256) void gemm_kernel(const float* __restrict__ X,
                                                   const float* __restrict__ W,
                                                   float* __restrict__ Hout) {
    __shared__ float Xs[GROWS][132];   // pad 128->132: lanes with differing row hit different banks
    int tid = threadIdx.x;
    int rowBase = blockIdx.x * GROWS;
    // stage X tile: 64 rows x 32 float4
    for (int i = tid; i < GROWS * 32; i += 256) {
        int r = i >> 5;
        int c4 = i & 31;
        float4 v = make_float4(0.f, 0.f, 0.f, 0.f);
        int gr = rowBase + r;
        if (gr < NNODES) v = *(const float4*)(X + (size_t)gr * HID + c4 * 4);
        Xs[r][c4 * 4 + 0] = v.x; Xs[r][c4 * 4 + 1] = v.y;
        Xs[r][c4 * 4 + 2] = v.z; Xs[r][c4 * 4 + 3] = v.w;
    }
    __syncthreads();
    int cg = tid & 15;   // 16 col-groups of 8 cols
    int rg = tid >> 4;   // 16 row-groups of 4 rows
    float acc[4][8];
    #pragma unroll
    for (int i = 0; i < 4; ++i)
        #pragma unroll
        for (int j = 0; j < 8; ++j) acc[i][j] = 0.f;

    #pragma unroll 4
    for (int k = 0; k < 128; ++k) {
        float4 w0 = *(const float4*)(W + k * HID + cg * 8);
        float4 w1 = *(const float4*)(W + k * HID + cg * 8 + 4);
        #pragma unroll
        for (int i = 0; i < 4; ++i) {
            float x = Xs[rg * 4 + i][k];
            acc[i][0] += x * w0.x; acc[i][1] += x * w0.y;
            acc[i][2] += x * w0.z; acc[i][3] += x * w0.w;
            acc[i][4] += x * w1.x; acc[i][5] += x * w1.y;
            acc[i][6] += x * w1.z; acc[i][7] += x * w1.w;
        }
    }
    #pragma unroll
    for (int i = 0; i < 4; ++i) {
        int gr = rowBase + rg * 4 + i;
        if (gr < NNODES) {
            float4 o0 = make_float4(acc[i][0], acc[i][1], acc[i][2], acc[i][3]);
            float4 o1 = make_float4(acc[i][4], acc[i][5], acc[i][6], acc[i][7]);
            *(float4*)(Hout + (size_t)gr * HID + cg * 8) = o0;
            *(float4*)(Hout + (size_t)gr * HID + cg * 8 + 4) = o1;
        }
    }
}

// ---------------------------------------------------------------- attention coefficients
__global__ void coef_kernel(const float* __restrict__ H, const float* __restrict__ a,
                            float* __restrict__ esrc, float* __restrict__ edst) {
    int idx = blockIdx.x * blockDim.x + threadIdx.x;   // n*8 + h
    if (idx >= NNODES * NHEAD) return;
    int h = idx & 7;
    int n = idx >> 3;
    const float* hp = H + (size_t)n * HID + h * HDIM;
    const float* ah = a + h * 2 * HDIM;
    float s = 0.f, t = 0.f;
    #pragma unroll
    for (int d = 0; d < HDIM; ++d) {
        float v = hp[d];
        s += v * ah[d];
        t += v * ah[HDIM + d];
    }
    esrc[idx] = s;
    edst[idx] = t;
}

// ---------------------------------------------------------------- per-dst softmax aggregation
__global__ __launch_bounds__(128) void aggregate_kernel(const int* __restrict__ offs,
                                                        const int* __restrict__ csr,
                                                        const float* __restrict__ esrc,
                                                        const float* __restrict__ edst,
                                                        const float* __restrict__ H,
                                                        float* __restrict__ out) {
    int n = blockIdx.x;
    int t = threadIdx.x;         // t = head*16 + d
    int head = t >> 4;
    int beg = offs[n], end = offs[n + 1];
    float ed = edst[n * NHEAD + head];
    float m = -1e30f;
    for (int i = beg; i < end; ++i) {
        int s = csr[i];
        float e = esrc[s * NHEAD + head] + ed;
        e = (e >= 0.f) ? e : 0.2f * e;
        m = fmaxf(m, e);
    }
    float acc = 0.f, den = 0.f;
    for (int i = beg; i < end; ++i) {
        int s = csr[i];
        float e = esrc[s * NHEAD + head] + ed;
        e = (e >= 0.f) ? e : 0.2f * e;
        float w = __expf(e - m);
        den += w;
        acc += w * H[(size_t)s * HID + t];
    }
    out[(size_t)n * HID + t] = acc / (den + 1e-16f);
}

// ---------------------------------------------------------------- BatchNorm
__global__ __launch_bounds__(256) void bn_stats_kernel(const float* __restrict__ X,
                                                       float* __restrict__ stats) {
    int t = threadIdx.x;
    int c = t & 127;
    int half = t >> 7;
    float s = 0.f, ss = 0.f;
    for (int r = blockIdx.x * 2 + half; r < NNODES; r += gridDim.x * 2) {
        float v = X[(size_t)r * HID + c];
        s += v;
        ss += v * v;
    }
    __shared__ float sm[256];
    sm[t] = s; __syncthreads();
    if (t < 128) atomicAdd(&stats[c], sm[t] + sm[t + 128]);
    __syncthreads();
    sm[t] = ss; __syncthreads();
    if (t < 128) atomicAdd(&stats[128 + c], sm[t] + sm[t + 128]);
}

__global__ void bn_finalize_kernel(float* __restrict__ stats, const float* __restrict__ g,
                                   const float* __restrict__ b) {
    int c = threadIdx.x;
    if (c < 128) {
        float mu = stats[c] / (float)NNODES;
        float var = stats[128 + c] / (float)NNODES - mu * mu;
        float rstd = rsqrtf(var + 1e-5f);
        float scale = g[c] * rstd;
        stats[256 + c] = scale;
        stats[384 + c] = b[c] - mu * scale;
    }
}

// mode 0: out = elu(bn(x))           (layer 1 -> h1)
// mode 1: out = skip + elu(bn(x))    (layer 2 -> h3_in)
// mode 2: out = bn(x)                (layer 3 -> d_out)
__global__ void apply_kernel(const float* __restrict__ X, const float* __restrict__ stats,
                             const float* __restrict__ skip, float* __restrict__ out,
                             int mode) {
    int i = blockIdx.x * blockDim.x + threadIdx.x;   // float4 index
    int total4 = NNODES * HID / 4;
    if (i >= total4) return;
    float4 v = ((const float4*)X)[i];
    int c4 = (i & 31) * 4;
    float4 sc = *(const float4*)(stats + 256 + c4);
    float4 sh = *(const float4*)(stats + 384 + c4);
    v.x = sc.x * v.x + sh.x;
    v.y = sc.y * v.y + sh.y;
    v.z = sc.z * v.z + sh.z;
    v.w = sc.w * v.w + sh.w;
    if (mode <= 1) {
        v.x = (v.x > 0.f) ? v.x : expm1f(v.x);
        v.y = (v.y > 0.f) ? v.y : expm1f(v.y);
        v.z = (v.z > 0.f) ? v.z : expm1f(v.z);
        v.w = (v.w > 0.f) ? v.w : expm1f(v.w);
    }
    if (mode == 1) {
        float4 s = ((const float4*)skip)[i];
        v.x += s.x; v.y += s.y; v.z += s.z; v.w += s.w;
    }
    ((float4*)out)[i] = v;
}

// ---------------------------------------------------------------- launch
extern "C" void kernel_launch(void* const* d_in, const int* in_sizes, int n_in,
                              void* d_out, int out_size, void* d_ws, size_t ws_size,
                              hipStream_t stream) {
    const float* x   = (const float*)d_in[0];
    const int* edge  = (const int*)d_in[1];
    const float* W1  = (const float*)d_in[2];
    const float* a1  = (const float*)d_in[3];
    const float* W2  = (const float*)d_in[4];
    const float* a2  = (const float*)d_in[5];
    const float* W3  = (const float*)d_in[6];
    const float* a3  = (const float*)d_in[7];
    const float* g1  = (const float*)d_in[8];
    const float* b1  = (const float*)d_in[9];
    const float* g2  = (const float*)d_in[10];
    const float* b2  = (const float*)d_in[11];
    const float* g3  = (const float*)d_in[12];
    const float* b3  = (const float*)d_in[13];
    float* outp      = (float*)d_out;

    // workspace carve-up
    char* p = (char*)d_ws;
    size_t cur = 0;
    auto carve = [&](size_t bytes) {
        void* r = p + cur;
        cur = align_up(cur + bytes, 256);
        return r;
    };
    int*   cnt   = (int*)carve(NNODES * sizeof(int));
    int*   offs  = (int*)carve((NNODES + 1) * sizeof(int));
    int*   csr   = (int*)carve(NEDGES * sizeof(int));
    float* hbuf  = (float*)carve((size_t)NNODES * HID * sizeof(float));
    float* agg   = (float*)carve((size_t)NNODES * HID * sizeof(float));
    float* h1    = (float*)carve((size_t)NNODES * HID * sizeof(float));
    float* h3in  = (float*)carve((size_t)NNODES * HID * sizeof(float));
    float* esrc  = (float*)carve((size_t)NNODES * NHEAD * sizeof(float));
    float* edst  = (float*)carve((size_t)NNODES * NHEAD * sizeof(float));
    float* stats = (float*)carve(512 * sizeof(float));

    const int EB = (NEDGES + 255) / 256;
    const int GB = (NNODES + GROWS - 1) / GROWS;
    const int CB = (NNODES * NHEAD + 255) / 256;
    const int AB = NNODES;
    const int PB = (NNODES * HID / 4 + 255) / 256;

    // ---- CSR build
    hipMemsetAsync(cnt, 0, NNODES * sizeof(int), stream);
    hist_kernel<<<EB, 256, 0, stream>>>(edge, cnt);
    scan_kernel<<<1, 1024, 0, stream>>>(cnt, offs);
    hipMemsetAsync(cnt, 0, NNODES * sizeof(int), stream);
    scatter_kernel<<<EB, 256, 0, stream>>>(edge, offs, cnt, csr);

    // ---- layer 1: h1 = elu(bn(gat(x, W1, a1)))
    gemm_kernel<<<GB, 256, 0, stream>>>(x, W1, hbuf);
    coef_kernel<<<CB, 256, 0, stream>>>(hbuf, a1, esrc, edst);
    aggregate_kernel<<<AB, 128, 0, stream>>>(offs, csr, esrc, edst, hbuf, agg);
    hipMemsetAsync(stats, 0, 256 * sizeof(float), stream);
    bn_stats_kernel<<<256, 256, 0, stream>>>(agg, stats);
    bn_finalize_kernel<<<1, 128, 0, stream>>>(stats, g1, b1);
    apply_kernel<<<PB, 256, 0, stream>>>(agg, stats, nullptr, h1, 0);

    // ---- layer 2: h3in = h1 + elu(bn(gat(h1, W2, a2)))
    gemm_kernel<<<GB, 256, 0, stream>>>(h1, W2, hbuf);
    coef_kernel<<<CB, 256, 0, stream>>>(hbuf, a2, esrc, edst);
    aggregate_kernel<<<AB, 128, 0, stream>>>(offs, csr, esrc, edst, hbuf, agg);
    hipMemsetAsync(stats, 0, 256 * sizeof(float), stream);
    bn_stats_kernel<<<256, 256, 0, stream>>>(agg, stats);
    bn_finalize_kernel<<<1, 128, 0, stream>>>(stats, g2, b2);
    apply_kernel<<<PB, 256, 0, stream>>>(agg, stats, h1, h3in, 1);

    // ---- layer 3: out = bn(gat(h3in, W3, a3))
    gemm_kernel<<<GB, 256, 0, stream>>>(h3in, W3, hbuf);
    coef_kernel<<<CB, 256, 0, stream>>>(hbuf, a3, esrc, edst);
    aggregate_kernel<<<AB, 128, 0, stream>>>(offs, csr, esrc, edst, hbuf, agg);
    hipMemsetAsync(stats, 0, 256 * sizeof(float), stream);
    bn_stats_kernel<<<256, 256, 0, stream>>>(agg, stats);
    bn_finalize_kernel<<<1, 128, 0, stream>>>(stats, g3, b3);
    apply_kernel<<<PB, 256, 0, stream>>>(agg, stats, nullptr, outp, 2);
}

// Round 2
// 759.757 us; speedup vs baseline: 1.2637x; 1.2637x over previous
//
#include <hip/hip_runtime.h>
#include <hip/hip_bf16.h>
#include <cstddef>

#define NNODES 50000
#define NEDGES 800000
#define HID 128
#define NHEAD 8
#define HDIM 16

static inline size_t align_up(size_t x, size_t a) { return (x + a - 1) & ~(a - 1); }

__device__ inline unsigned short f2bf(float f) {
    unsigned u = __float_as_uint(f);
    unsigned r = (u + 0x7fffu + ((u >> 16) & 1u)) >> 16;
    return (unsigned short)r;
}

// ---------------------------------------------------------------- CSR build
__global__ void hist_kernel(const int* __restrict__ edge, int* __restrict__ cnt) {
    int e = blockIdx.x * blockDim.x + threadIdx.x;
    if (e < NEDGES) {
        int d = edge[NEDGES + e];
        atomicAdd(&cnt[d], 1);
    }
}

// thread-sequential chunks + one block scan (replaces 49 Hillis-Steele rounds)
__global__ __launch_bounds__(1024) void scan_kernel(const int* __restrict__ cnt,
                                                    int* __restrict__ offs) {
    __shared__ int sm[1024];
    const int ITEMS = 49;   // 1024*49 >= 50000
    int t = threadIdx.x;
    int base = t * ITEMS;
    int lim = base + ITEMS; if (lim > NNODES) lim = NNODES;
    int s = 0;
    for (int i = base; i < lim; ++i) s += cnt[i];
    sm[t] = s;
    __syncthreads();
    for (int off = 1; off < 1024; off <<= 1) {
        int v = (t >= off) ? sm[t - off] : 0;
        __syncthreads();
        sm[t] += v;
        __syncthreads();
    }
    int run = sm[t] - s;   // exclusive prefix of this thread's chunk
    for (int i = base; i < lim; ++i) { offs[i] = run; run += cnt[i]; }
    if (t == 0) offs[NNODES] = NEDGES;
}

__global__ void scatter_kernel(const int* __restrict__ edge, const int* __restrict__ offs,
                               int* __restrict__ cursor, int* __restrict__ csr) {
    int e = blockIdx.x * blockDim.x + threadIdx.x;
    if (e < NEDGES) {
        int s = edge[e];
        int d = edge[NEDGES + e];
        int p = offs[d] + atomicAdd(&cursor[d], 1);
        csr[p] = s;
    }
}

// ---------------------------------------------------------------- GEMM [N,128]x[128,128]
// Fused epilogue: writes bf16 copy of h + per-(node,head) esrc/edst attention coefs.
// fp32 h is never materialized (nothing downstream needs it).
#define GROWS 64
__global__ __launch_bounds__(256) void gemm_kernel(const float* __restrict__ X,
                                                   const float* __restrict__ W,
                                                   const float* __restrict__ a,
                                                   unsigned int* __restrict__ Hb, // bf16x2 [N,64]
                                                   float* __restrict__ esrc,
                                                   float* __restrict__ edst) {
    __shared__ float Xs[GROWS][132];   // +4 pad: kills bank conflicts on column reads
    int tid = threadIdx.x;
    int rowBase = blockIdx.x * GROWS;
    for (int i = tid; i < GROWS * 32; i += 256) {
        int r = i >> 5;
        int c4 = i & 31;
        float4 v = make_float4(0.f, 0.f, 0.f, 0.f);
        int gr = rowBase + r;
        if (gr < NNODES) v = *(const float4*)(X + (size_t)gr * HID + c4 * 4);
        Xs[r][c4 * 4 + 0] = v.x; Xs[r][c4 * 4 + 1] = v.y;
        Xs[r][c4 * 4 + 2] = v.z; Xs[r][c4 * 4 + 3] = v.w;
    }
    __syncthreads();
    int cg = tid & 15;   // col-group: 8 cols each
    int rg = tid >> 4;   // row-group: 4 rows each
    float acc[4][8];
    #pragma unroll
    for (int i = 0; i < 4; ++i)
        #pragma unroll
        for (int j = 0; j < 8; ++j) acc[i][j] = 0.f;

    #pragma unroll 4
    for (int k = 0; k < 128; ++k) {
        float4 w0 = *(const float4*)(W + k * HID + cg * 8);
        float4 w1 = *(const float4*)(W + k * HID + cg * 8 + 4);
        #pragma unroll
        for (int i = 0; i < 4; ++i) {
            float x = Xs[rg * 4 + i][k];
            acc[i][0] += x * w0.x; acc[i][1] += x * w0.y;
            acc[i][2] += x * w0.z; acc[i][3] += x * w0.w;
            acc[i][4] += x * w1.x; acc[i][5] += x * w1.y;
            acc[i][6] += x * w1.z; acc[i][7] += x * w1.w;
        }
    }

    int h = cg >> 1;             // head owned by this col-group pair
    int half = (cg & 1) * 8;     // which 8 of the head's 16 dims
    #pragma unroll
    for (int i = 0; i < 4; ++i) {
        int gr = rowBase + rg * 4 + i;
        // bf16 h row (uint = 2 packed bf16)
        unsigned int pk[4];
        #pragma unroll
        for (int j = 0; j < 4; ++j)
            pk[j] = (unsigned int)f2bf(acc[i][2 * j]) |
                    ((unsigned int)f2bf(acc[i][2 * j + 1]) << 16);
        // attention coefs from fp32 accumulators (exact vs separate fp32 kernel)
        float es = 0.f, ev = 0.f;
        #pragma unroll
        for (int j = 0; j < 8; ++j) {
            float v = acc[i][j];
            es += v * a[h * 32 + half + j];
            ev += v * a[h * 32 + 16 + half + j];
        }
        es += __shfl_xor(es, 1);
        ev += __shfl_xor(ev, 1);
        if (gr < NNODES) {
            *(uint4*)(Hb + (size_t)gr * 64 + cg * 4) = *(uint4*)pk;
            if (!(cg & 1)) {
                esrc[gr * NHEAD + h] = es;
                edst[gr * NHEAD + h] = ev;
            }
        }
    }
}

// ---------------------------------------------------------------- per-dst softmax aggregation
// One wave per node. Softmax computed WITHOUT the max pass: the shift cancels
// exactly in num/den, and |e| <~ 6 here so exp() cannot overflow.
__global__ __launch_bounds__(256) void aggregate_kernel(const int* __restrict__ offs,
                                                        const int* __restrict__ csr,
                                                        const float* __restrict__ esrc,
                                                        const float* __restrict__ edst,
                                                        const unsigned int* __restrict__ Hb,
                                                        float* __restrict__ out) {
    int tid = threadIdx.x;
    int n = blockIdx.x * 4 + (tid >> 6);
    if (n >= NNODES) return;
    int lane = tid & 63;       // owns channels 2*lane, 2*lane+1
    int head = lane >> 3;
    int beg = offs[n], end = offs[n + 1];
    float ed = edst[n * NHEAD + head];
    float acc0 = 0.f, acc1 = 0.f, den = 0.f;
    for (int i = beg; i < end; ++i) {
        int s = csr[i];
        float e = esrc[s * NHEAD + head] + ed;
        e = (e >= 0.f) ? e : 0.2f * e;
        float w = __expf(e);
        den += w;
        unsigned int hv = Hb[(size_t)s * 64 + lane];
        acc0 += w * __uint_as_float(hv << 16);
        acc1 += w * __uint_as_float(hv & 0xffff0000u);
    }
    float inv = 1.f / (den + 1e-16f);
    float2 o = make_float2(acc0 * inv, acc1 * inv);
    *(float2*)(out + (size_t)n * HID + lane * 2) = o;
}

// ---------------------------------------------------------------- BatchNorm
__global__ __launch_bounds__(256) void bn_stats_kernel(const float* __restrict__ X,
                                                       float* __restrict__ stats) {
    int t = threadIdx.x;
    int c = t & 127;
    int half = t >> 7;
    float s = 0.f, ss = 0.f;
    for (int r = blockIdx.x * 2 + half; r < NNODES; r += gridDim.x * 2) {
        float v = X[(size_t)r * HID + c];
        s += v;
        ss += v * v;
    }
    __shared__ float sm[256];
    sm[t] = s; __syncthreads();
    if (t < 128) atomicAdd(&stats[c], sm[t] + sm[t + 128]);
    __syncthreads();
    sm[t] = ss; __syncthreads();
    if (t < 128) atomicAdd(&stats[128 + c], sm[t] + sm[t + 128]);
}

__global__ void bn_finalize_kernel(float* __restrict__ stats, const float* __restrict__ g,
                                   const float* __restrict__ b) {
    int c = threadIdx.x;
    if (c < 128) {
        float mu = stats[c] / (float)NNODES;
        float var = stats[128 + c] / (float)NNODES - mu * mu;
        float rstd = rsqrtf(var + 1e-5f);
        float scale = g[c] * rstd;
        stats[256 + c] = scale;
        stats[384 + c] = b[c] - mu * scale;
    }
}

// mode 0: out = elu(bn(x)); mode 1: out = skip + elu(bn(x)); mode 2: out = bn(x)
__global__ void apply_kernel(const float* __restrict__ X, const float* __restrict__ stats,
                             const float* __restrict__ skip, float* __restrict__ out,
                             int mode) {
    int i = blockIdx.x * blockDim.x + threadIdx.x;
    int total4 = NNODES * HID / 4;
    if (i >= total4) return;
    float4 v = ((const float4*)X)[i];
    int c4 = (i & 31) * 4;
    float4 sc = *(const float4*)(stats + 256 + c4);
    float4 sh = *(const float4*)(stats + 384 + c4);
    v.x = sc.x * v.x + sh.x;
    v.y = sc.y * v.y + sh.y;
    v.z = sc.z * v.z + sh.z;
    v.w = sc.w * v.w + sh.w;
    if (mode <= 1) {
        v.x = (v.x > 0.f) ? v.x : expm1f(v.x);
        v.y = (v.y > 0.f) ? v.y : expm1f(v.y);
        v.z = (v.z > 0.f) ? v.z : expm1f(v.z);
        v.w = (v.w > 0.f) ? v.w : expm1f(v.w);
    }
    if (mode == 1) {
        float4 s = ((const float4*)skip)[i];
        v.x += s.x; v.y += s.y; v.z += s.z; v.w += s.w;
    }
    ((float4*)out)[i] = v;
}

// ---------------------------------------------------------------- launch
extern "C" void kernel_launch(void* const* d_in, const int* in_sizes, int n_in,
                              void* d_out, int out_size, void* d_ws, size_t ws_size,
                              hipStream_t stream) {
    const float* x   = (const float*)d_in[0];
    const int* edge  = (const int*)d_in[1];
    const float* W1  = (const float*)d_in[2];
    const float* a1  = (const float*)d_in[3];
    const float* W2  = (const float*)d_in[4];
    const float* a2  = (const float*)d_in[5];
    const float* W3  = (const float*)d_in[6];
    const float* a3  = (const float*)d_in[7];
    const float* g1  = (const float*)d_in[8];
    const float* b1  = (const float*)d_in[9];
    const float* g2  = (const float*)d_in[10];
    const float* b2  = (const float*)d_in[11];
    const float* g3  = (const float*)d_in[12];
    const float* b3  = (const float*)d_in[13];
    float* outp      = (float*)d_out;

    char* p = (char*)d_ws;
    size_t cur = 0;
    auto carve = [&](size_t bytes) {
        void* r = p + cur;
        cur = align_up(cur + bytes, 256);
        return r;
    };
    int*   cnt   = (int*)carve(2 * NNODES * sizeof(int));   // cnt + cursor, one memset
    int*   cursor = cnt + NNODES;
    int*   offs  = (int*)carve((NNODES + 1) * sizeof(int));
    int*   csr   = (int*)carve(NEDGES * sizeof(int));
    unsigned int* hb = (unsigned int*)carve((size_t)NNODES * 64 * sizeof(unsigned int)); // bf16 h
    float* agg   = (float*)carve((size_t)NNODES * HID * sizeof(float));
    float* h1    = (float*)carve((size_t)NNODES * HID * sizeof(float));
    float* h3in  = (float*)carve((size_t)NNODES * HID * sizeof(float));
    float* esrc  = (float*)carve((size_t)NNODES * NHEAD * sizeof(float));
    float* edst  = (float*)carve((size_t)NNODES * NHEAD * sizeof(float));
    float* stats = (float*)carve(512 * sizeof(float));

    const int EB = (NEDGES + 255) / 256;
    const int GB = (NNODES + GROWS - 1) / GROWS;
    const int AB = (NNODES + 3) / 4;
    const int PB = (NNODES * HID / 4 + 255) / 256;

    // ---- CSR build
    hipMemsetAsync(cnt, 0, 2 * NNODES * sizeof(int), stream);
    hist_kernel<<<EB, 256, 0, stream>>>(edge, cnt);
    scan_kernel<<<1, 1024, 0, stream>>>(cnt, offs);
    scatter_kernel<<<EB, 256, 0, stream>>>(edge, offs, cursor, csr);

    // ---- layer 1
    gemm_kernel<<<GB, 256, 0, stream>>>(x, W1, a1, hb, esrc, edst);
    aggregate_kernel<<<AB, 256, 0, stream>>>(offs, csr, esrc, edst, hb, agg);
    hipMemsetAsync(stats, 0, 256 * sizeof(float), stream);
    bn_stats_kernel<<<256, 256, 0, stream>>>(agg, stats);
    bn_finalize_kernel<<<1, 128, 0, stream>>>(stats, g1, b1);
    apply_kernel<<<PB, 256, 0, stream>>>(agg, stats, nullptr, h1, 0);

    // ---- layer 2
    gemm_kernel<<<GB, 256, 0, stream>>>(h1, W2, a2, hb, esrc, edst);
    aggregate_kernel<<<AB, 256, 0, stream>>>(offs, csr, esrc, edst, hb, agg);
    hipMemsetAsync(stats, 0, 256 * sizeof(float), stream);
    bn_stats_kernel<<<256, 256, 0, stream>>>(agg, stats);
    bn_finalize_kernel<<<1, 128, 0, stream>>>(stats, g2, b2);
    apply_kernel<<<PB, 256, 0, stream>>>(agg, stats, h1, h3in, 1);

    // ---- layer 3
    gemm_kernel<<<GB, 256, 0, stream>>>(h3in, W3, a3, hb, esrc, edst);
    aggregate_kernel<<<AB, 256, 0, stream>>>(offs, csr, esrc, edst, hb, agg);
    hipMemsetAsync(stats, 0, 256 * sizeof(float), stream);
    bn_stats_kernel<<<256, 256, 0, stream>>>(agg, stats);
    bn_finalize_kernel<<<1, 128, 0, stream>>>(stats, g3, b3);
    apply_kernel<<<PB, 256, 0, stream>>>(agg, stats, nullptr, outp, 2);
}

// Round 3
// 622.801 us; speedup vs baseline: 1.5416x; 1.2199x over previous
//
#include <hip/hip_runtime.h>
#include <hip/hip_bf16.h>
#include <cstddef>

#define NNODES 50000
#define NEDGES 800000
#define HID 128
#define NHEAD 8
#define HDIM 16

static inline size_t align_up(size_t x, size_t a) { return (x + a - 1) & ~(a - 1); }

__device__ inline unsigned short f2bf(float f) {
    unsigned u = __float_as_uint(f);
    unsigned r = (u + 0x7fffu + ((u >> 16) & 1u)) >> 16;
    return (unsigned short)r;
}

// ---------------------------------------------------------------- CSR build
__global__ void hist_kernel(const int* __restrict__ edge, int* __restrict__ cnt) {
    int e = blockIdx.x * blockDim.x + threadIdx.x;
    if (e < NEDGES) {
        int d = edge[NEDGES + e];
        atomicAdd(&cnt[d], 1);
    }
}

__global__ __launch_bounds__(1024) void scan_kernel(const int* __restrict__ cnt,
                                                    int* __restrict__ offs) {
    __shared__ int sm[1024];
    const int ITEMS = 49;   // 1024*49 >= 50000
    int t = threadIdx.x;
    int base = t * ITEMS;
    int lim = base + ITEMS; if (lim > NNODES) lim = NNODES;
    int s = 0;
    for (int i = base; i < lim; ++i) s += cnt[i];
    sm[t] = s;
    __syncthreads();
    for (int off = 1; off < 1024; off <<= 1) {
        int v = (t >= off) ? sm[t - off] : 0;
        __syncthreads();
        sm[t] += v;
        __syncthreads();
    }
    int run = sm[t] - s;
    for (int i = base; i < lim; ++i) { offs[i] = run; run += cnt[i]; }
    if (t == 0) offs[NNODES] = NEDGES;
}

__global__ void scatter_kernel(const int* __restrict__ edge, const int* __restrict__ offs,
                               int* __restrict__ cursor, int* __restrict__ csr) {
    int e = blockIdx.x * blockDim.x + threadIdx.x;
    if (e < NEDGES) {
        int s = edge[e];
        int d = edge[NEDGES + e];
        int p = offs[d] + atomicAdd(&cursor[d], 1);
        csr[p] = s;
    }
}

// ---------------------------------------------------------------- GEMM [N,128]x[128,128]
// Fused epilogue: bf16 h rows + per-(node,head) esrc/edst attention coefs.
#define GROWS 64
__global__ __launch_bounds__(256) void gemm_kernel(const float* __restrict__ X,
                                                   const float* __restrict__ W,
                                                   const float* __restrict__ a,
                                                   unsigned int* __restrict__ Hb, // bf16x2 [N,64]
                                                   float* __restrict__ esrc,
                                                   float* __restrict__ edst) {
    __shared__ float Xs[GROWS][132];
    int tid = threadIdx.x;
    int rowBase = blockIdx.x * GROWS;
    for (int i = tid; i < GROWS * 32; i += 256) {
        int r = i >> 5;
        int c4 = i & 31;
        float4 v = make_float4(0.f, 0.f, 0.f, 0.f);
        int gr = rowBase + r;
        if (gr < NNODES) v = *(const float4*)(X + (size_t)gr * HID + c4 * 4);
        Xs[r][c4 * 4 + 0] = v.x; Xs[r][c4 * 4 + 1] = v.y;
        Xs[r][c4 * 4 + 2] = v.z; Xs[r][c4 * 4 + 3] = v.w;
    }
    __syncthreads();
    int cg = tid & 15;
    int rg = tid >> 4;
    float acc[4][8];
    #pragma unroll
    for (int i = 0; i < 4; ++i)
        #pragma unroll
        for (int j = 0; j < 8; ++j) acc[i][j] = 0.f;

    #pragma unroll 4
    for (int k = 0; k < 128; ++k) {
        float4 w0 = *(const float4*)(W + k * HID + cg * 8);
        float4 w1 = *(const float4*)(W + k * HID + cg * 8 + 4);
        #pragma unroll
        for (int i = 0; i < 4; ++i) {
            float x = Xs[rg * 4 + i][k];
            acc[i][0] += x * w0.x; acc[i][1] += x * w0.y;
            acc[i][2] += x * w0.z; acc[i][3] += x * w0.w;
            acc[i][4] += x * w1.x; acc[i][5] += x * w1.y;
            acc[i][6] += x * w1.z; acc[i][7] += x * w1.w;
        }
    }

    int h = cg >> 1;
    int half = (cg & 1) * 8;
    #pragma unroll
    for (int i = 0; i < 4; ++i) {
        int gr = rowBase + rg * 4 + i;
        unsigned int pk[4];
        #pragma unroll
        for (int j = 0; j < 4; ++j)
            pk[j] = (unsigned int)f2bf(acc[i][2 * j]) |
                    ((unsigned int)f2bf(acc[i][2 * j + 1]) << 16);
        float es = 0.f, ev = 0.f;
        #pragma unroll
        for (int j = 0; j < 8; ++j) {
            float v = acc[i][j];
            es += v * a[h * 32 + half + j];
            ev += v * a[h * 32 + 16 + half + j];
        }
        es += __shfl_xor(es, 1);
        ev += __shfl_xor(ev, 1);
        if (gr < NNODES) {
            *(uint4*)(Hb + (size_t)gr * 64 + cg * 4) = *(uint4*)pk;
            if (!(cg & 1)) {
                esrc[gr * NHEAD + h] = es;
                edst[gr * NHEAD + h] = ev;
            }
        }
    }
}

// ---------------------------------------------------------------- per-dst softmax aggregation
// One wave per node, 8-wide edge batching: 8 csr loads, then 8 esrc + 8 Hb
// gathers all in flight at once (breaks the serial csr->gather dependent chain).
// Tail edges handled by index-clamp + w=0 predication (no serial remainder).
__global__ __launch_bounds__(256) void aggregate_kernel(const int* __restrict__ offs,
                                                        const int* __restrict__ csr,
                                                        const float* __restrict__ esrc,
                                                        const float* __restrict__ edst,
                                                        const unsigned int* __restrict__ Hb,
                                                        float* __restrict__ out) {
    int tid = threadIdx.x;
    int n = blockIdx.x * 4 + (tid >> 6);
    if (n >= NNODES) return;
    int lane = tid & 63;       // owns channels 2*lane, 2*lane+1
    int head = lane >> 3;
    int beg = offs[n], end = offs[n + 1];
    float ed = edst[n * NHEAD + head];
    float acc0 = 0.f, acc1 = 0.f, den = 0.f;
    for (int i = beg; i < end; i += 8) {
        int ss[8];
        #pragma unroll
        for (int j = 0; j < 8; ++j) {
            int k = i + j;
            if (k > end - 1) k = end - 1;   // clamp: duplicate load, masked below
            ss[j] = csr[k];
        }
        float ee[8];
        unsigned int hh[8];
        #pragma unroll
        for (int j = 0; j < 8; ++j) ee[j] = esrc[ss[j] * NHEAD + head];
        #pragma unroll
        for (int j = 0; j < 8; ++j) hh[j] = Hb[(size_t)ss[j] * 64 + lane];
        #pragma unroll
        for (int j = 0; j < 8; ++j) {
            float e = ee[j] + ed;
            e = (e >= 0.f) ? e : 0.2f * e;
            float w = (i + j < end) ? __expf(e) : 0.f;
            den += w;
            acc0 += w * __uint_as_float(hh[j] << 16);
            acc1 += w * __uint_as_float(hh[j] & 0xffff0000u);
        }
    }
    float inv = 1.f / (den + 1e-16f);
    float2 o = make_float2(acc0 * inv, acc1 * inv);
    *(float2*)(out + (size_t)n * HID + lane * 2) = o;
}

// ---------------------------------------------------------------- BatchNorm
__global__ __launch_bounds__(256) void bn_stats_kernel(const float* __restrict__ X,
                                                       float* __restrict__ stats) {
    int t = threadIdx.x;
    int c = t & 127;
    int half = t >> 7;
    float s = 0.f, ss = 0.f;
    for (int r = blockIdx.x * 2 + half; r < NNODES; r += gridDim.x * 2) {
        float v = X[(size_t)r * HID + c];
        s += v;
        ss += v * v;
    }
    __shared__ float sm[256];
    sm[t] = s; __syncthreads();
    if (t < 128) atomicAdd(&stats[c], sm[t] + sm[t + 128]);
    __syncthreads();
    sm[t] = ss; __syncthreads();
    if (t < 128) atomicAdd(&stats[128 + c], sm[t] + sm[t + 128]);
}

__global__ void bn_finalize_kernel(float* __restrict__ stats, const float* __restrict__ g,
                                   const float* __restrict__ b) {
    int c = threadIdx.x;
    if (c < 128) {
        float mu = stats[c] / (float)NNODES;
        float var = stats[128 + c] / (float)NNODES - mu * mu;
        float rstd = rsqrtf(var + 1e-5f);
        float scale = g[c] * rstd;
        stats[256 + c] = scale;
        stats[384 + c] = b[c] - mu * scale;
    }
}

// mode 0: out = elu(bn(x)); mode 1: out = skip + elu(bn(x)); mode 2: out = bn(x)
__global__ void apply_kernel(const float* __restrict__ X, const float* __restrict__ stats,
                             const float* __restrict__ skip, float* __restrict__ out,
                             int mode) {
    int i = blockIdx.x * blockDim.x + threadIdx.x;
    int total4 = NNODES * HID / 4;
    if (i >= total4) return;
    float4 v = ((const float4*)X)[i];
    int c4 = (i & 31) * 4;
    float4 sc = *(const float4*)(stats + 256 + c4);
    float4 sh = *(const float4*)(stats + 384 + c4);
    v.x = sc.x * v.x + sh.x;
    v.y = sc.y * v.y + sh.y;
    v.z = sc.z * v.z + sh.z;
    v.w = sc.w * v.w + sh.w;
    if (mode <= 1) {
        v.x = (v.x > 0.f) ? v.x : expm1f(v.x);
        v.y = (v.y > 0.f) ? v.y : expm1f(v.y);
        v.z = (v.z > 0.f) ? v.z : expm1f(v.z);
        v.w = (v.w > 0.f) ? v.w : expm1f(v.w);
    }
    if (mode == 1) {
        float4 s = ((const float4*)skip)[i];
        v.x += s.x; v.y += s.y; v.z += s.z; v.w += s.w;
    }
    ((float4*)out)[i] = v;
}

// ---------------------------------------------------------------- launch
extern "C" void kernel_launch(void* const* d_in, const int* in_sizes, int n_in,
                              void* d_out, int out_size, void* d_ws, size_t ws_size,
                              hipStream_t stream) {
    const float* x   = (const float*)d_in[0];
    const int* edge  = (const int*)d_in[1];
    const float* W1  = (const float*)d_in[2];
    const float* a1  = (const float*)d_in[3];
    const float* W2  = (const float*)d_in[4];
    const float* a2  = (const float*)d_in[5];
    const float* W3  = (const float*)d_in[6];
    const float* a3  = (const float*)d_in[7];
    const float* g1  = (const float*)d_in[8];
    const float* b1  = (const float*)d_in[9];
    const float* g2  = (const float*)d_in[10];
    const float* b2  = (const float*)d_in[11];
    const float* g3  = (const float*)d_in[12];
    const float* b3  = (const float*)d_in[13];
    float* outp      = (float*)d_out;

    char* p = (char*)d_ws;
    size_t cur = 0;
    auto carve = [&](size_t bytes) {
        void* r = p + cur;
        cur = align_up(cur + bytes, 256);
        return r;
    };
    int*   cnt    = (int*)carve(2 * NNODES * sizeof(int));
    int*   cursor = cnt + NNODES;
    int*   offs   = (int*)carve((NNODES + 1) * sizeof(int));
    int*   csr    = (int*)carve(NEDGES * sizeof(int));
    unsigned int* hb = (unsigned int*)carve((size_t)NNODES * 64 * sizeof(unsigned int));
    float* agg    = (float*)carve((size_t)NNODES * HID * sizeof(float));
    float* h1     = (float*)carve((size_t)NNODES * HID * sizeof(float));
    float* h3in   = (float*)carve((size_t)NNODES * HID * sizeof(float));
    float* esrc   = (float*)carve((size_t)NNODES * NHEAD * sizeof(float));
    float* edst   = (float*)carve((size_t)NNODES * NHEAD * sizeof(float));
    float* stats  = (float*)carve(3 * 512 * sizeof(float));   // one zero-fill for all 3 layers
    float* stats1 = stats, *stats2 = stats + 512, *stats3 = stats + 1024;

    const int EB = (NEDGES + 255) / 256;
    const int GB = (NNODES + GROWS - 1) / GROWS;
    const int AB = (NNODES + 3) / 4;
    const int PB = (NNODES * HID / 4 + 255) / 256;

    // ---- CSR build + stats zero-fill (single memset for all three layers)
    hipMemsetAsync(cnt, 0, 2 * NNODES * sizeof(int), stream);
    hipMemsetAsync(stats, 0, 3 * 512 * sizeof(float), stream);
    hist_kernel<<<EB, 256, 0, stream>>>(edge, cnt);
    scan_kernel<<<1, 1024, 0, stream>>>(cnt, offs);
    scatter_kernel<<<EB, 256, 0, stream>>>(edge, offs, cursor, csr);

    // ---- layer 1
    gemm_kernel<<<GB, 256, 0, stream>>>(x, W1, a1, hb, esrc, edst);
    aggregate_kernel<<<AB, 256, 0, stream>>>(offs, csr, esrc, edst, hb, agg);
    bn_stats_kernel<<<256, 256, 0, stream>>>(agg, stats1);
    bn_finalize_kernel<<<1, 128, 0, stream>>>(stats1, g1, b1);
    apply_kernel<<<PB, 256, 0, stream>>>(agg, stats1, nullptr, h1, 0);

    // ---- layer 2
    gemm_kernel<<<GB, 256, 0, stream>>>(h1, W2, a2, hb, esrc, edst);
    aggregate_kernel<<<AB, 256, 0, stream>>>(offs, csr, esrc, edst, hb, agg);
    bn_stats_kernel<<<256, 256, 0, stream>>>(agg, stats2);
    bn_finalize_kernel<<<1, 128, 0, stream>>>(stats2, g2, b2);
    apply_kernel<<<PB, 256, 0, stream>>>(agg, stats2, h1, h3in, 1);

    // ---- layer 3
    gemm_kernel<<<GB, 256, 0, stream>>>(h3in, W3, a3, hb, esrc, edst);
    aggregate_kernel<<<AB, 256, 0, stream>>>(offs, csr, esrc, edst, hb, agg);
    bn_stats_kernel<<<256, 256, 0, stream>>>(agg, stats3);
    bn_finalize_kernel<<<1, 128, 0, stream>>>(stats3, g3, b3);
    apply_kernel<<<PB, 256, 0, stream>>>(agg, stats3, nullptr, outp, 2);
}

// Round 4
// 547.068 us; speedup vs baseline: 1.7551x; 1.1384x over previous
//
#include <hip/hip_runtime.h>
#include <hip/hip_bf16.h>
#include <cstddef>

#define NNODES 50000
#define NEDGES 800000
#define HID 128
#define NHEAD 8
#define HDIM 16
#define SCAN_BLK 256
#define SCAN_NB ((NNODES + SCAN_BLK - 1) / SCAN_BLK)   // 196

static inline size_t align_up(size_t x, size_t a) { return (x + a - 1) & ~(a - 1); }

__device__ inline unsigned short f2bf(float f) {
    unsigned u = __float_as_uint(f);
    unsigned r = (u + 0x7fffu + ((u >> 16) & 1u)) >> 16;
    return (unsigned short)r;
}

// ---------------------------------------------------------------- CSR build
__global__ void hist_kernel(const int* __restrict__ edge, int* __restrict__ cnt) {
    int e = blockIdx.x * blockDim.x + threadIdx.x;
    if (e < NEDGES) {
        int d = edge[NEDGES + e];
        atomicAdd(&cnt[d], 1);
    }
}

// hierarchical scan: per-block sums -> scan of block sums -> emit
__global__ __launch_bounds__(256) void scan_partial_kernel(const int* __restrict__ cnt,
                                                           int* __restrict__ bsum) {
    int t = threadIdx.x;
    int i = blockIdx.x * 256 + t;
    __shared__ int sm[256];
    sm[t] = (i < NNODES) ? cnt[i] : 0;
    __syncthreads();
    for (int off = 128; off > 0; off >>= 1) {
        if (t < off) sm[t] += sm[t + off];
        __syncthreads();
    }
    if (t == 0) bsum[blockIdx.x] = sm[0];
}

__global__ __launch_bounds__(256) void scan_bsum_kernel(const int* __restrict__ bsum,
                                                        int* __restrict__ boffs) {
    int t = threadIdx.x;
    int v = (t < SCAN_NB) ? bsum[t] : 0;
    __shared__ int sm[256];
    sm[t] = v;
    __syncthreads();
    for (int off = 1; off < 256; off <<= 1) {
        int x = (t >= off) ? sm[t - off] : 0;
        __syncthreads();
        sm[t] += x;
        __syncthreads();
    }
    if (t < SCAN_NB) boffs[t] = sm[t] - v;   // exclusive
}

__global__ __launch_bounds__(256) void scan_emit_kernel(const int* __restrict__ cnt,
                                                        const int* __restrict__ boffs,
                                                        int* __restrict__ offs) {
    int t = threadIdx.x;
    int i = blockIdx.x * 256 + t;
    int v = (i < NNODES) ? cnt[i] : 0;
    __shared__ int sm[256];
    sm[t] = v;
    __syncthreads();
    for (int off = 1; off < 256; off <<= 1) {
        int x = (t >= off) ? sm[t - off] : 0;
        __syncthreads();
        sm[t] += x;
        __syncthreads();
    }
    if (i < NNODES) offs[i] = boffs[blockIdx.x] + sm[t] - v;
    if (i == 0) offs[NNODES] = NEDGES;
}

__global__ void scatter_kernel(const int* __restrict__ edge, const int* __restrict__ offs,
                               int* __restrict__ cursor, int* __restrict__ csr) {
    int e = blockIdx.x * blockDim.x + threadIdx.x;
    if (e < NEDGES) {
        int s = edge[e];
        int d = edge[NEDGES + e];
        int p = offs[d] + atomicAdd(&cursor[d], 1);
        csr[p] = s;
    }
}

// ---------------------------------------------------------------- GEMM [N,128]x[128,128]
// Prologue modes (fused elementwise from the PREVIOUS layer, bit-identical
// to the old apply_kernel):
//   mode 0: X = Xin                                  (layer 1)
//   mode 1: X = elu(bn(Xin; stats)); also write X to Hw (=h1, needed for skip)
//   mode 2: X = skip + elu(bn(Xin; stats))           (h3_in, never materialized)
// Epilogue: bf16 h row + per-(node,head) esrc/edst attention coefs.
#define GROWS 64
__global__ __launch_bounds__(256) void gemm_kernel(const float* __restrict__ Xin,
                                                   const float* __restrict__ skip,
                                                   const float* __restrict__ stats,
                                                   const float* __restrict__ W,
                                                   const float* __restrict__ a,
                                                   float* __restrict__ Hw,
                                                   unsigned int* __restrict__ Hb, // bf16x2 [N,64]
                                                   float* __restrict__ esrc,
                                                   float* __restrict__ edst,
                                                   int mode) {
    __shared__ float Xs[GROWS][132];
    int tid = threadIdx.x;
    int rowBase = blockIdx.x * GROWS;
    for (int i = tid; i < GROWS * 32; i += 256) {
        int r = i >> 5;
        int c4 = i & 31;
        float4 v = make_float4(0.f, 0.f, 0.f, 0.f);
        int gr = rowBase + r;
        if (gr < NNODES) {
            v = *(const float4*)(Xin + (size_t)gr * HID + c4 * 4);
            if (mode >= 1) {
                int ch = c4 * 4;
                float4 sc = *(const float4*)(stats + 256 + ch);
                float4 sh = *(const float4*)(stats + 384 + ch);
                v.x = sc.x * v.x + sh.x;
                v.y = sc.y * v.y + sh.y;
                v.z = sc.z * v.z + sh.z;
                v.w = sc.w * v.w + sh.w;
                v.x = (v.x > 0.f) ? v.x : expm1f(v.x);
                v.y = (v.y > 0.f) ? v.y : expm1f(v.y);
                v.z = (v.z > 0.f) ? v.z : expm1f(v.z);
                v.w = (v.w > 0.f) ? v.w : expm1f(v.w);
                if (mode == 2) {
                    float4 s = *(const float4*)(skip + (size_t)gr * HID + c4 * 4);
                    v.x += s.x; v.y += s.y; v.z += s.z; v.w += s.w;
                } else {
                    *(float4*)(Hw + (size_t)gr * HID + c4 * 4) = v;
                }
            }
        }
        Xs[r][c4 * 4 + 0] = v.x; Xs[r][c4 * 4 + 1] = v.y;
        Xs[r][c4 * 4 + 2] = v.z; Xs[r][c4 * 4 + 3] = v.w;
    }
    __syncthreads();
    int cg = tid & 15;
    int rg = tid >> 4;
    float acc[4][8];
    #pragma unroll
    for (int i = 0; i < 4; ++i)
        #pragma unroll
        for (int j = 0; j < 8; ++j) acc[i][j] = 0.f;

    #pragma unroll 4
    for (int k = 0; k < 128; ++k) {
        float4 w0 = *(const float4*)(W + k * HID + cg * 8);
        float4 w1 = *(const float4*)(W + k * HID + cg * 8 + 4);
        #pragma unroll
        for (int i = 0; i < 4; ++i) {
            float x = Xs[rg * 4 + i][k];
            acc[i][0] += x * w0.x; acc[i][1] += x * w0.y;
            acc[i][2] += x * w0.z; acc[i][3] += x * w0.w;
            acc[i][4] += x * w1.x; acc[i][5] += x * w1.y;
            acc[i][6] += x * w1.z; acc[i][7] += x * w1.w;
        }
    }

    int h = cg >> 1;
    int half = (cg & 1) * 8;
    #pragma unroll
    for (int i = 0; i < 4; ++i) {
        int gr = rowBase + rg * 4 + i;
        unsigned int pk[4];
        #pragma unroll
        for (int j = 0; j < 4; ++j)
            pk[j] = (unsigned int)f2bf(acc[i][2 * j]) |
                    ((unsigned int)f2bf(acc[i][2 * j + 1]) << 16);
        float es = 0.f, ev = 0.f;
        #pragma unroll
        for (int j = 0; j < 8; ++j) {
            float v = acc[i][j];
            es += v * a[h * 32 + half + j];
            ev += v * a[h * 32 + 16 + half + j];
        }
        es += __shfl_xor(es, 1);
        ev += __shfl_xor(ev, 1);
        if (gr < NNODES) {
            *(uint4*)(Hb + (size_t)gr * 64 + cg * 4) = *(uint4*)pk;
            if (!(cg & 1)) {
                esrc[gr * NHEAD + h] = es;
                edst[gr * NHEAD + h] = ev;
            }
        }
    }
}

// ---------------------------------------------------------------- per-dst softmax aggregation
// One wave per node, 8-wide edge batching (8 independent gather chains in flight).
__global__ __launch_bounds__(256) void aggregate_kernel(const int* __restrict__ offs,
                                                        const int* __restrict__ csr,
                                                        const float* __restrict__ esrc,
                                                        const float* __restrict__ edst,
                                                        const unsigned int* __restrict__ Hb,
                                                        float* __restrict__ out) {
    int tid = threadIdx.x;
    int n = blockIdx.x * 4 + (tid >> 6);
    if (n >= NNODES) return;
    int lane = tid & 63;       // owns channels 2*lane, 2*lane+1
    int head = lane >> 3;
    int beg = offs[n], end = offs[n + 1];
    float ed = edst[n * NHEAD + head];
    float acc0 = 0.f, acc1 = 0.f, den = 0.f;
    for (int i = beg; i < end; i += 8) {
        int ss[8];
        #pragma unroll
        for (int j = 0; j < 8; ++j) {
            int k = i + j;
            if (k > end - 1) k = end - 1;   // clamp: duplicate load, masked below
            ss[j] = csr[k];
        }
        float ee[8];
        unsigned int hh[8];
        #pragma unroll
        for (int j = 0; j < 8; ++j) ee[j] = esrc[ss[j] * NHEAD + head];
        #pragma unroll
        for (int j = 0; j < 8; ++j) hh[j] = Hb[(size_t)ss[j] * 64 + lane];
        #pragma unroll
        for (int j = 0; j < 8; ++j) {
            float e = ee[j] + ed;
            e = (e >= 0.f) ? e : 0.2f * e;
            float w = (i + j < end) ? __expf(e) : 0.f;
            den += w;
            acc0 += w * __uint_as_float(hh[j] << 16);
            acc1 += w * __uint_as_float(hh[j] & 0xffff0000u);
        }
    }
    float inv = 1.f / (den + 1e-16f);
    float2 o = make_float2(acc0 * inv, acc1 * inv);
    *(float2*)(out + (size_t)n * HID + lane * 2) = o;
}

// ---------------------------------------------------------------- BatchNorm
__global__ __launch_bounds__(256) void bn_stats_kernel(const float* __restrict__ X,
                                                       float* __restrict__ stats) {
    int t = threadIdx.x;
    int c = t & 127;
    int half = t >> 7;
    float s = 0.f, ss = 0.f;
    for (int r = blockIdx.x * 2 + half; r < NNODES; r += gridDim.x * 2) {
        float v = X[(size_t)r * HID + c];
        s += v;
        ss += v * v;
    }
    __shared__ float sm[256];
    sm[t] = s; __syncthreads();
    if (t < 128) atomicAdd(&stats[c], sm[t] + sm[t + 128]);
    __syncthreads();
    sm[t] = ss; __syncthreads();
    if (t < 128) atomicAdd(&stats[128 + c], sm[t] + sm[t + 128]);
}

__global__ void bn_finalize_kernel(float* __restrict__ stats, const float* __restrict__ g,
                                   const float* __restrict__ b) {
    int c = threadIdx.x;
    if (c < 128) {
        float mu = stats[c] / (float)NNODES;
        float var = stats[128 + c] / (float)NNODES - mu * mu;
        float rstd = rsqrtf(var + 1e-5f);
        float scale = g[c] * rstd;
        stats[256 + c] = scale;
        stats[384 + c] = b[c] - mu * scale;
    }
}

// final output: out = bn(x) only (layers 1/2 elementwise is fused into gemm prologue)
__global__ void final_apply_kernel(const float* __restrict__ X, const float* __restrict__ stats,
                                   float* __restrict__ out) {
    int i = blockIdx.x * blockDim.x + threadIdx.x;
    int total4 = NNODES * HID / 4;
    if (i >= total4) return;
    float4 v = ((const float4*)X)[i];
    int c4 = (i & 31) * 4;
    float4 sc = *(const float4*)(stats + 256 + c4);
    float4 sh = *(const float4*)(stats + 384 + c4);
    v.x = sc.x * v.x + sh.x;
    v.y = sc.y * v.y + sh.y;
    v.z = sc.z * v.z + sh.z;
    v.w = sc.w * v.w + sh.w;
    ((float4*)out)[i] = v;
}

// ---------------------------------------------------------------- launch
extern "C" void kernel_launch(void* const* d_in, const int* in_sizes, int n_in,
                              void* d_out, int out_size, void* d_ws, size_t ws_size,
                              hipStream_t stream) {
    const float* x   = (const float*)d_in[0];
    const int* edge  = (const int*)d_in[1];
    const float* W1  = (const float*)d_in[2];
    const float* a1  = (const float*)d_in[3];
    const float* W2  = (const float*)d_in[4];
    const float* a2  = (const float*)d_in[5];
    const float* W3  = (const float*)d_in[6];
    const float* a3  = (const float*)d_in[7];
    const float* g1  = (const float*)d_in[8];
    const float* b1  = (const float*)d_in[9];
    const float* g2  = (const float*)d_in[10];
    const float* b2  = (const float*)d_in[11];
    const float* g3  = (const float*)d_in[12];
    const float* b3  = (const float*)d_in[13];
    float* outp      = (float*)d_out;

    char* p = (char*)d_ws;
    size_t cur = 0;
    auto carve = [&](size_t bytes) {
        void* r = p + cur;
        cur = align_up(cur + bytes, 256);
        return r;
    };
    int*   cnt    = (int*)carve(2 * NNODES * sizeof(int));
    int*   cursor = cnt + NNODES;
    int*   offs   = (int*)carve((NNODES + 1) * sizeof(int));
    int*   csr    = (int*)carve(NEDGES * sizeof(int));
    int*   bsum   = (int*)carve(SCAN_NB * sizeof(int));
    int*   boffs  = (int*)carve(SCAN_NB * sizeof(int));
    unsigned int* hb = (unsigned int*)carve((size_t)NNODES * 64 * sizeof(unsigned int));
    float* agg    = (float*)carve((size_t)NNODES * HID * sizeof(float));
    float* h1     = (float*)carve((size_t)NNODES * HID * sizeof(float));
    float* esrc   = (float*)carve((size_t)NNODES * NHEAD * sizeof(float));
    float* edst   = (float*)carve((size_t)NNODES * NHEAD * sizeof(float));
    float* stats  = (float*)carve(3 * 512 * sizeof(float));
    float* stats1 = stats, *stats2 = stats + 512, *stats3 = stats + 1024;

    const int EB = (NEDGES + 255) / 256;
    const int GB = (NNODES + GROWS - 1) / GROWS;
    const int AB = (NNODES + 3) / 4;
    const int PB = (NNODES * HID / 4 + 255) / 256;

    // ---- CSR build + stats zero-fill
    hipMemsetAsync(cnt, 0, 2 * NNODES * sizeof(int), stream);
    hipMemsetAsync(stats, 0, 3 * 512 * sizeof(float), stream);
    hist_kernel<<<EB, 256, 0, stream>>>(edge, cnt);
    scan_partial_kernel<<<SCAN_NB, 256, 0, stream>>>(cnt, bsum);
    scan_bsum_kernel<<<1, 256, 0, stream>>>(bsum, boffs);
    scan_emit_kernel<<<SCAN_NB, 256, 0, stream>>>(cnt, boffs, offs);
    scatter_kernel<<<EB, 256, 0, stream>>>(edge, offs, cursor, csr);

    // ---- layer 1
    gemm_kernel<<<GB, 256, 0, stream>>>(x, nullptr, nullptr, W1, a1, nullptr, hb, esrc, edst, 0);
    aggregate_kernel<<<AB, 256, 0, stream>>>(offs, csr, esrc, edst, hb, agg);
    bn_stats_kernel<<<256, 256, 0, stream>>>(agg, stats1);
    bn_finalize_kernel<<<1, 128, 0, stream>>>(stats1, g1, b1);

    // ---- layer 2 (gemm prologue applies elu(bn1(agg)) and writes h1)
    gemm_kernel<<<GB, 256, 0, stream>>>(agg, nullptr, stats1, W2, a2, h1, hb, esrc, edst, 1);
    aggregate_kernel<<<AB, 256, 0, stream>>>(offs, csr, esrc, edst, hb, agg);
    bn_stats_kernel<<<256, 256, 0, stream>>>(agg, stats2);
    bn_finalize_kernel<<<1, 128, 0, stream>>>(stats2, g2, b2);

    // ---- layer 3 (gemm prologue computes h1 + elu(bn2(agg)); h3_in never materialized)
    gemm_kernel<<<GB, 256, 0, stream>>>(agg, h1, stats2, W3, a3, nullptr, hb, esrc, edst, 2);
    aggregate_kernel<<<AB, 256, 0, stream>>>(offs, csr, esrc, edst, hb, agg);
    bn_stats_kernel<<<256, 256, 0, stream>>>(agg, stats3);
    bn_finalize_kernel<<<1, 128, 0, stream>>>(stats3, g3, b3);
    final_apply_kernel<<<PB, 256, 0, stream>>>(agg, stats3, outp);
}

// Round 5
// 543.717 us; speedup vs baseline: 1.7659x; 1.0062x over previous
//
#include <hip/hip_runtime.h>
#include <hip/hip_bf16.h>
#include <cstddef>

#define NNODES 50000
#define NEDGES 800000
#define HID 128
#define NHEAD 8
#define HDIM 16
#define SCAN_BLK 256
#define SCAN_NB ((NNODES + SCAN_BLK - 1) / SCAN_BLK)   // 196

typedef __attribute__((ext_vector_type(8))) short short8;
typedef __attribute__((ext_vector_type(4))) float floatx4;

static inline size_t align_up(size_t x, size_t a) { return (x + a - 1) & ~(a - 1); }

__device__ inline unsigned short f2bf(float f) {
    unsigned u = __float_as_uint(f);
    unsigned r = (u + 0x7fffu + ((u >> 16) & 1u)) >> 16;
    return (unsigned short)r;
}
__device__ inline float bf_lo(unsigned int u) { return __uint_as_float(u << 16); }
__device__ inline float bf_hi(unsigned int u) { return __uint_as_float(u & 0xffff0000u); }

// ---------------------------------------------------------------- CSR build
__global__ void hist_kernel(const int* __restrict__ edge, int* __restrict__ cnt) {
    int e = blockIdx.x * blockDim.x + threadIdx.x;
    if (e < NEDGES) {
        int d = edge[NEDGES + e];
        atomicAdd(&cnt[d], 1);
    }
}

__global__ __launch_bounds__(256) void scan_partial_kernel(const int* __restrict__ cnt,
                                                           int* __restrict__ bsum) {
    int t = threadIdx.x;
    int i = blockIdx.x * 256 + t;
    __shared__ int sm[256];
    sm[t] = (i < NNODES) ? cnt[i] : 0;
    __syncthreads();
    for (int off = 128; off > 0; off >>= 1) {
        if (t < off) sm[t] += sm[t + off];
        __syncthreads();
    }
    if (t == 0) bsum[blockIdx.x] = sm[0];
}

__global__ __launch_bounds__(256) void scan_bsum_kernel(const int* __restrict__ bsum,
                                                        int* __restrict__ boffs) {
    int t = threadIdx.x;
    int v = (t < SCAN_NB) ? bsum[t] : 0;
    __shared__ int sm[256];
    sm[t] = v;
    __syncthreads();
    for (int off = 1; off < 256; off <<= 1) {
        int x = (t >= off) ? sm[t - off] : 0;
        __syncthreads();
        sm[t] += x;
        __syncthreads();
    }
    if (t < SCAN_NB) boffs[t] = sm[t] - v;   // exclusive
}

__global__ __launch_bounds__(256) void scan_emit_kernel(const int* __restrict__ cnt,
                                                        const int* __restrict__ boffs,
                                                        int* __restrict__ offs) {
    int t = threadIdx.x;
    int i = blockIdx.x * 256 + t;
    int v = (i < NNODES) ? cnt[i] : 0;
    __shared__ int sm[256];
    sm[t] = v;
    __syncthreads();
    for (int off = 1; off < 256; off <<= 1) {
        int x = (t >= off) ? sm[t - off] : 0;
        __syncthreads();
        sm[t] += x;
        __syncthreads();
    }
    if (i < NNODES) offs[i] = boffs[blockIdx.x] + sm[t] - v;
    if (i == 0) offs[NNODES] = NEDGES;
}

__global__ void scatter_kernel(const int* __restrict__ edge, const int* __restrict__ offs,
                               int* __restrict__ cursor, int* __restrict__ csr) {
    int e = blockIdx.x * blockDim.x + threadIdx.x;
    if (e < NEDGES) {
        int s = edge[e];
        int d = edge[NEDGES + e];
        int p = offs[d] + atomicAdd(&cursor[d], 1);
        csr[p] = s;
    }
}

// ---------------------------------------------------------------- weight pre-transpose
// Wt[layer][n*128+k] = bf16(W[k*128+n]); coalesced reads, scattered 2B writes (tiny).
__global__ __launch_bounds__(256) void wconv_kernel(const float* __restrict__ W1,
                                                    const float* __restrict__ W2,
                                                    const float* __restrict__ W3,
                                                    unsigned short* __restrict__ Wt) {
    int b = blockIdx.x;             // 0..191
    int layer = b >> 6;
    const float* W = (layer == 0) ? W1 : ((layer == 1) ? W2 : W3);
    int idx = (b & 63) * 256 + threadIdx.x;   // k*128+n
    int n = idx & 127;
    int k = idx >> 7;
    Wt[layer * 16384 + n * 128 + k] = f2bf(W[idx]);
}

// ---------------------------------------------------------------- MFMA GEMM [N,128]x[128,128]
// Prologue modes (fused elementwise from the previous layer):
//   mode 0: X = Xin
//   mode 1: X = elu(bn(Xin; stats)); also write X to Hw (=h1, skip source)
//   mode 2: X = skip + elu(bn(Xin; stats))   (h3_in never materialized)
// Epilogue via LDS transpose: bf16 Hb rows (coalesced uint4) + esrc/edst coefs.
#define GROWS 64
#define ASTRIDE 136   // 128 + 8 pad: ds_read_b128 column access <= 2-way bank alias (free)
__global__ __launch_bounds__(256) void gemm_kernel(const float* __restrict__ Xin,
                                                   const float* __restrict__ skip,
                                                   const float* __restrict__ stats,
                                                   const unsigned short* __restrict__ Wt,
                                                   const float* __restrict__ a,
                                                   float* __restrict__ Hw,
                                                   unsigned short* __restrict__ Hb,
                                                   float* __restrict__ esrc,
                                                   float* __restrict__ edst,
                                                   int mode) {
    __shared__ unsigned short As[GROWS * ASTRIDE];   // A: [m][k]
    __shared__ unsigned short Bs[128 * ASTRIDE];     // B: [n][k]  (= W^T)
    int tid = threadIdx.x;
    int rowBase = blockIdx.x * GROWS;

    // ---- stage B: copy Wt (bf16 [n][k]) -> Bs with padded stride
    for (int i = tid; i < 128 * 16; i += 256) {
        int n = i >> 4, seg = i & 15;
        *(uint4*)(&Bs[n * ASTRIDE + seg * 8]) = *(const uint4*)(Wt + n * 128 + seg * 8);
    }

    // ---- stage A: fp32 load + fused elementwise + bf16 convert -> As
    {
        int r = tid >> 2;
        int cs = (tid & 3) * 32;
        int gr = rowBase + r;
        float4 vv[8];
        if (gr < NNODES) {
            #pragma unroll
            for (int j = 0; j < 8; ++j)
                vv[j] = *(const float4*)(Xin + (size_t)gr * HID + cs + j * 4);
            if (mode >= 1) {
                #pragma unroll
                for (int j = 0; j < 8; ++j) {
                    int ch = cs + j * 4;
                    float4 sc = *(const float4*)(stats + 256 + ch);
                    float4 sh = *(const float4*)(stats + 384 + ch);
                    float4 v = vv[j];
                    v.x = sc.x * v.x + sh.x;
                    v.y = sc.y * v.y + sh.y;
                    v.z = sc.z * v.z + sh.z;
                    v.w = sc.w * v.w + sh.w;
                    v.x = (v.x > 0.f) ? v.x : expm1f(v.x);
                    v.y = (v.y > 0.f) ? v.y : expm1f(v.y);
                    v.z = (v.z > 0.f) ? v.z : expm1f(v.z);
                    v.w = (v.w > 0.f) ? v.w : expm1f(v.w);
                    if (mode == 2) {
                        float4 s = *(const float4*)(skip + (size_t)gr * HID + ch);
                        v.x += s.x; v.y += s.y; v.z += s.z; v.w += s.w;
                    }
                    vv[j] = v;
                }
                if (mode == 1) {
                    #pragma unroll
                    for (int j = 0; j < 8; ++j)
                        *(float4*)(Hw + (size_t)gr * HID + cs + j * 4) = vv[j];
                }
            }
        } else {
            #pragma unroll
            for (int j = 0; j < 8; ++j) vv[j] = make_float4(0.f, 0.f, 0.f, 0.f);
        }
        unsigned int pk[16];
        #pragma unroll
        for (int j = 0; j < 8; ++j) {
            pk[2 * j]     = (unsigned int)f2bf(vv[j].x) | ((unsigned int)f2bf(vv[j].y) << 16);
            pk[2 * j + 1] = (unsigned int)f2bf(vv[j].z) | ((unsigned int)f2bf(vv[j].w) << 16);
        }
        #pragma unroll
        for (int q = 0; q < 4; ++q)
            *(uint4*)(&As[r * ASTRIDE + cs + q * 8]) =
                make_uint4(pk[4 * q], pk[4 * q + 1], pk[4 * q + 2], pk[4 * q + 3]);
    }
    __syncthreads();

    // ---- MFMA main: wave w -> rows w*16..+16, all 128 cols (8 n-tiles, K=128)
    int wv = tid >> 6;
    int lane = tid & 63;
    int l15 = lane & 15;
    int quad = lane >> 4;
    const unsigned short* Arow = &As[(wv * 16 + l15) * ASTRIDE + quad * 8];
    short8 af[4];
    #pragma unroll
    for (int c = 0; c < 4; ++c) af[c] = *(const short8*)(Arow + c * 32);

    floatx4 acc[8];
    #pragma unroll
    for (int h = 0; h < 8; ++h) {
        acc[h] = (floatx4){0.f, 0.f, 0.f, 0.f};
        const unsigned short* Brow = &Bs[(h * 16 + l15) * ASTRIDE + quad * 8];
        #pragma unroll
        for (int c = 0; c < 4; ++c) {
            short8 bf = *(const short8*)(Brow + c * 32);
            acc[h] = __builtin_amdgcn_mfma_f32_16x16x32_bf16(af[c], bf, acc[h], 0, 0, 0);
        }
    }
    __syncthreads();   // done reading As/Bs; reuse As for the C tile

    // ---- scatter C (bf16) into As: lane holds rows quad*4+reg, col h*16+l15
    #pragma unroll
    for (int h = 0; h < 8; ++h) {
        #pragma unroll
        for (int reg = 0; reg < 4; ++reg)
            As[(wv * 16 + quad * 4 + reg) * ASTRIDE + h * 16 + l15] = f2bf(acc[h][reg]);
    }
    __syncthreads();

    // ---- phase 2: coalesced Hb stores + per-(node,head) attention coefs
    {
        int r = tid >> 2;
        int hp = tid & 3;                 // head pair
        int gr = rowBase + r;
        const unsigned short* row = &As[r * ASTRIDE + hp * 32];
        uint4 u[4];
        #pragma unroll
        for (int q = 0; q < 4; ++q) u[q] = *(const uint4*)(row + q * 8);
        if (gr < NNODES) {
            uint4* dst = (uint4*)(Hb + (size_t)gr * HID + hp * 32);
            #pragma unroll
            for (int q = 0; q < 4; ++q) dst[q] = u[q];
            float f[32];
            #pragma unroll
            for (int q = 0; q < 4; ++q) {
                unsigned int* pu = (unsigned int*)&u[q];
                #pragma unroll
                for (int j = 0; j < 4; ++j) {
                    f[q * 8 + 2 * j]     = bf_lo(pu[j]);
                    f[q * 8 + 2 * j + 1] = bf_hi(pu[j]);
                }
            }
            int h0 = hp * 2, h1 = hp * 2 + 1;
            float es0 = 0.f, ev0 = 0.f, es1 = 0.f, ev1 = 0.f;
            #pragma unroll
            for (int j = 0; j < 16; ++j) {
                es0 += f[j] * a[h0 * 32 + j];
                ev0 += f[j] * a[h0 * 32 + 16 + j];
                es1 += f[16 + j] * a[h1 * 32 + j];
                ev1 += f[16 + j] * a[h1 * 32 + 16 + j];
            }
            esrc[gr * NHEAD + h0] = es0;
            esrc[gr * NHEAD + h1] = es1;
            edst[gr * NHEAD + h0] = ev0;
            edst[gr * NHEAD + h1] = ev1;
        }
    }
}

// ---------------------------------------------------------------- per-dst softmax aggregation
// One wave per node, 16-wide edge batching (16 independent gather chains in flight).
__global__ __launch_bounds__(256) void aggregate_kernel(const int* __restrict__ offs,
                                                        const int* __restrict__ csr,
                                                        const float* __restrict__ esrc,
                                                        const float* __restrict__ edst,
                                                        const unsigned int* __restrict__ Hb,
                                                        float* __restrict__ out) {
    int tid = threadIdx.x;
    int n = blockIdx.x * 4 + (tid >> 6);
    if (n >= NNODES) return;
    int lane = tid & 63;       // owns channels 2*lane, 2*lane+1
    int head = lane >> 3;
    int beg = offs[n], end = offs[n + 1];
    float ed = edst[n * NHEAD + head];
    float acc0 = 0.f, acc1 = 0.f, den = 0.f;
    for (int i = beg; i < end; i += 16) {
        int ss[16];
        #pragma unroll
        for (int j = 0; j < 16; ++j) {
            int k = i + j;
            if (k > end - 1) k = end - 1;   // clamp: duplicate load, masked below
            ss[j] = csr[k];
        }
        float ee[16];
        unsigned int hh[16];
        #pragma unroll
        for (int j = 0; j < 16; ++j) ee[j] = esrc[ss[j] * NHEAD + head];
        #pragma unroll
        for (int j = 0; j < 16; ++j) hh[j] = Hb[(size_t)ss[j] * 64 + lane];
        #pragma unroll
        for (int j = 0; j < 16; ++j) {
            float e = ee[j] + ed;
            e = (e >= 0.f) ? e : 0.2f * e;
            float w = (i + j < end) ? __expf(e) : 0.f;
            den += w;
            acc0 += w * bf_lo(hh[j]);
            acc1 += w * bf_hi(hh[j]);
        }
    }
    float inv = 1.f / (den + 1e-16f);
    float2 o = make_float2(acc0 * inv, acc1 * inv);
    *(float2*)(out + (size_t)n * HID + lane * 2) = o;
}

// ---------------------------------------------------------------- BatchNorm
__global__ __launch_bounds__(256) void bn_stats_kernel(const float* __restrict__ X,
                                                       float* __restrict__ stats) {
    int t = threadIdx.x;
    int c = t & 127;
    int half = t >> 7;
    float s = 0.f, ss = 0.f;
    for (int r = blockIdx.x * 2 + half; r < NNODES; r += gridDim.x * 2) {
        float v = X[(size_t)r * HID + c];
        s += v;
        ss += v * v;
    }
    __shared__ float sm[256];
    sm[t] = s; __syncthreads();
    if (t < 128) atomicAdd(&stats[c], sm[t] + sm[t + 128]);
    __syncthreads();
    sm[t] = ss; __syncthreads();
    if (t < 128) atomicAdd(&stats[128 + c], sm[t] + sm[t + 128]);
}

__global__ void bn_finalize_kernel(float* __restrict__ stats, const float* __restrict__ g,
                                   const float* __restrict__ b) {
    int c = threadIdx.x;
    if (c < 128) {
        float mu = stats[c] / (float)NNODES;
        float var = stats[128 + c] / (float)NNODES - mu * mu;
        float rstd = rsqrtf(var + 1e-5f);
        float scale = g[c] * rstd;
        stats[256 + c] = scale;
        stats[384 + c] = b[c] - mu * scale;
    }
}

__global__ void final_apply_kernel(const float* __restrict__ X, const float* __restrict__ stats,
                                   float* __restrict__ out) {
    int i = blockIdx.x * blockDim.x + threadIdx.x;
    int total4 = NNODES * HID / 4;
    if (i >= total4) return;
    float4 v = ((const float4*)X)[i];
    int c4 = (i & 31) * 4;
    float4 sc = *(const float4*)(stats + 256 + c4);
    float4 sh = *(const float4*)(stats + 384 + c4);
    v.x = sc.x * v.x + sh.x;
    v.y = sc.y * v.y + sh.y;
    v.z = sc.z * v.z + sh.z;
    v.w = sc.w * v.w + sh.w;
    ((float4*)out)[i] = v;
}

// ---------------------------------------------------------------- launch
extern "C" void kernel_launch(void* const* d_in, const int* in_sizes, int n_in,
                              void* d_out, int out_size, void* d_ws, size_t ws_size,
                              hipStream_t stream) {
    const float* x   = (const float*)d_in[0];
    const int* edge  = (const int*)d_in[1];
    const float* W1  = (const float*)d_in[2];
    const float* a1  = (const float*)d_in[3];
    const float* W2  = (const float*)d_in[4];
    const float* a2  = (const float*)d_in[5];
    const float* W3  = (const float*)d_in[6];
    const float* a3  = (const float*)d_in[7];
    const float* g1  = (const float*)d_in[8];
    const float* b1  = (const float*)d_in[9];
    const float* g2  = (const float*)d_in[10];
    const float* b2  = (const float*)d_in[11];
    const float* g3  = (const float*)d_in[12];
    const float* b3  = (const float*)d_in[13];
    float* outp      = (float*)d_out;

    char* p = (char*)d_ws;
    size_t cur = 0;
    auto carve = [&](size_t bytes) {
        void* r = p + cur;
        cur = align_up(cur + bytes, 256);
        return r;
    };
    int*   cnt    = (int*)carve(2 * NNODES * sizeof(int));
    int*   cursor = cnt + NNODES;
    int*   offs   = (int*)carve((NNODES + 1) * sizeof(int));
    int*   csr    = (int*)carve(NEDGES * sizeof(int));
    int*   bsum   = (int*)carve(SCAN_NB * sizeof(int));
    int*   boffs  = (int*)carve(SCAN_NB * sizeof(int));
    unsigned short* wt = (unsigned short*)carve(3 * 16384 * sizeof(unsigned short));
    unsigned short* hb = (unsigned short*)carve((size_t)NNODES * HID * sizeof(unsigned short));
    float* agg    = (float*)carve((size_t)NNODES * HID * sizeof(float));
    float* h1     = (float*)carve((size_t)NNODES * HID * sizeof(float));
    float* esrc   = (float*)carve((size_t)NNODES * NHEAD * sizeof(float));
    float* edst   = (float*)carve((size_t)NNODES * NHEAD * sizeof(float));
    float* stats  = (float*)carve(3 * 512 * sizeof(float));
    float* stats1 = stats, *stats2 = stats + 512, *stats3 = stats + 1024;

    const int EB = (NEDGES + 255) / 256;
    const int GB = (NNODES + GROWS - 1) / GROWS;
    const int AB = (NNODES + 3) / 4;
    const int PB = (NNODES * HID / 4 + 255) / 256;

    // ---- CSR build + weight transpose + stats zero-fill
    hipMemsetAsync(cnt, 0, 2 * NNODES * sizeof(int), stream);
    hipMemsetAsync(stats, 0, 3 * 512 * sizeof(float), stream);
    wconv_kernel<<<192, 256, 0, stream>>>(W1, W2, W3, wt);
    hist_kernel<<<EB, 256, 0, stream>>>(edge, cnt);
    scan_partial_kernel<<<SCAN_NB, 256, 0, stream>>>(cnt, bsum);
    scan_bsum_kernel<<<1, 256, 0, stream>>>(bsum, boffs);
    scan_emit_kernel<<<SCAN_NB, 256, 0, stream>>>(cnt, boffs, offs);
    scatter_kernel<<<EB, 256, 0, stream>>>(edge, offs, cursor, csr);

    // ---- layer 1
    gemm_kernel<<<GB, 256, 0, stream>>>(x, nullptr, nullptr, wt, a1, nullptr, hb, esrc, edst, 0);
    aggregate_kernel<<<AB, 256, 0, stream>>>(offs, csr, esrc, edst, (const unsigned int*)hb, agg);
    bn_stats_kernel<<<256, 256, 0, stream>>>(agg, stats1);
    bn_finalize_kernel<<<1, 128, 0, stream>>>(stats1, g1, b1);

    // ---- layer 2
    gemm_kernel<<<GB, 256, 0, stream>>>(agg, nullptr, stats1, wt + 16384, a2, h1, hb, esrc, edst, 1);
    aggregate_kernel<<<AB, 256, 0, stream>>>(offs, csr, esrc, edst, (const unsigned int*)hb, agg);
    bn_stats_kernel<<<256, 256, 0, stream>>>(agg, stats2);
    bn_finalize_kernel<<<1, 128, 0, stream>>>(stats2, g2, b2);

    // ---- layer 3
    gemm_kernel<<<GB, 256, 0, stream>>>(agg, h1, stats2, wt + 32768, a3, nullptr, hb, esrc, edst, 2);
    aggregate_kernel<<<AB, 256, 0, stream>>>(offs, csr, esrc, edst, (const unsigned int*)hb, agg);
    bn_stats_kernel<<<256, 256, 0, stream>>>(agg, stats3);
    bn_finalize_kernel<<<1, 128, 0, stream>>>(stats3, g3, b3);
    final_apply_kernel<<<PB, 256, 0, stream>>>(agg, stats3, outp);
}